// Round 6
// baseline (319.226 us; speedup 1.0000x reference)
//
#include <hip/hip_runtime.h>

// Problem: B=256, N=131072, F=16. Two-pass causal FIR with masking:
//   v[i] = (i>=16) ? x[i] + sum_{j<16} h[j]*x[i-1-j] : 0
//   y[i] = (i>=16) ? v[i] + sum_{j<16} h[15-j]*v[i-1-j] : 0
// For i >= 32, y = 33-tap conv with g = conv([1,h],[1,rev(h)]).
// i in [16,32) explicit; i < 16 zero.
//
// R7 results: 94us (worse than R6's 82), VALU 34%, HBM 27%, occ 57%,
// conflicts 0, VGPR 36, traffic optimal (67+131 MB). Nothing saturated and
// nothing caps occupancy below 8 waves/SIMD -> the machine can't FEED the
// CUs: 32768 tiny WGs (~350-cyc bodies) need 349 WG/us from the command
// processor. Dispatch-rate bound.
// R7 -> R8: persistent grid. 2048 WGs (8/CU), each grid-strides 16 tiles.
// Body identical to R7. WG lifetime x16, dispatch pressure /16.
// Falsifier: occ >= 85% but dur >= 80us -> wall is L1 9x read amplification
// -> next round: LDS staging under persistent grid.

#define NROW 131072
#define NTILES 32768     // 1024 outputs per tile, 128 tiles per row
#define PGRID 2048       // 8 WGs per CU, persistent

typedef float f32x4 __attribute__((ext_vector_type(4)));

__global__ void compute_g_kernel(const float* __restrict__ h, float* __restrict__ g) {
    int m = threadIdx.x;
    if (m < 33) {
        float s = 0.f;
#pragma unroll
        for (int a = 0; a <= 16; ++a) {
            int b = m - a;
            if (b >= 0 && b <= 16) {
                float ka = (a == 0) ? 1.f : h[a - 1];
                float kb = (b == 0) ? 1.f : h[16 - b];
                s += ka * kb;
            }
        }
        g[m] = s;
    }
}

__global__ __launch_bounds__(256) void fir2_kernel(const float* __restrict__ x,
                                                   const float* __restrict__ g,
                                                   const float* __restrict__ h,
                                                   float* __restrict__ y) {
    const int t = (int)threadIdx.x;

    // ---- g[0..32]: uniform indices off a uniform pointer -> s_load (SGPRs),
    // hoisted out of the tile loop ----
    float gg[33];
#pragma unroll
    for (int m = 0; m < 33; ++m) gg[m] = g[m];

#pragma unroll 1
    for (int tile = (int)blockIdx.x; tile < NTILES; tile += PGRID) {
        const int row = tile >> 7;          // 128 tiles per row
        const int blk = tile & 127;
        const int p0 = (blk << 10) + 4 * t;             // this thread's 4 outputs
        const float* __restrict__ xr = x + (size_t)row * NROW;
        float* __restrict__ yr = y + (size_t)row * NROW;

        // ---- window w[j] = x[p0-32+j], j=0..35: 9 coalesced float4 loads ----
        float w[36];
        const float* __restrict__ wp = xr + p0 - 32;    // 16B-aligned
        if (blk != 0) {                                 // hot path: no predicates
#pragma unroll
            for (int q = 0; q < 9; ++q) {
                const f32x4 v = *(const f32x4*)(wp + 4 * q);  // offset:16q folds
                w[4 * q + 0] = v.x; w[4 * q + 1] = v.y;
                w[4 * q + 2] = v.z; w[4 * q + 3] = v.w;
            }
        } else {                                        // first tile of row only
#pragma unroll
            for (int q = 0; q < 9; ++q) {
                const int gidx = p0 - 32 + 4 * q;
                f32x4 v = (f32x4)(0.f);
                if (gidx >= 0) v = *(const f32x4*)(xr + gidx);
                w[4 * q + 0] = v.x; w[4 * q + 1] = v.y;
                w[4 * q + 2] = v.z; w[4 * q + 3] = v.w;
            }
        }

        f32x4 o;
#pragma unroll
        for (int c = 0; c < 4; ++c) {
            float s = 0.f;
#pragma unroll
            for (int m = 0; m < 33; ++m) s = fmaf(gg[m], w[c + 32 - m], s);
            o[c] = s;
        }
        // y never re-read: nt store keeps x L3-resident
        __builtin_nontemporal_store(o, (f32x4*)(yr + p0));

        // ---- Cold boundary fixup: outputs [0,32), first tile of row, lanes 0..7 ----
        if (blk == 0 && t < 8) {
            f32x4 ofix = (f32x4)(0.f);
            if (t >= 4) {
                float hh[16];
#pragma unroll
                for (int j = 0; j < 16; ++j) hh[j] = h[j];   // uniform -> s_load
                // v[16+u] = x[16+u] + sum_j h[j] x[15+u-j]; x[0..47] are L1-hot
                float vloc[16];
#pragma unroll
                for (int u = 0; u < 16; ++u) {
                    const int p = 16 + u;
                    float s = xr[p];
#pragma unroll
                    for (int j = 0; j < 16; ++j)
                        s = fmaf(hh[j], xr[p - 1 - j], s);
                    vloc[u] = s;
                }
                // y[p] = v[p] + sum_{j<=p-17} h[15-j] v[p-1-j]; static indexing
#pragma unroll
                for (int p = 16; p < 32; ++p) {
                    float s = vloc[p - 16];
#pragma unroll
                    for (int j = 0; j < 16; ++j)
                        if (j <= p - 17) s = fmaf(hh[15 - j], vloc[p - 17 - j], s);
                    if ((p >> 2) == t) ofix[p & 3] = s;      // static reg index
                }
            }
            __builtin_nontemporal_store(ofix, (f32x4*)(yr + 4 * t));  // overwrite
        }
    }
}

extern "C" void kernel_launch(void* const* d_in, const int* in_sizes, int n_in,
                              void* d_out, int out_size, void* d_ws, size_t ws_size,
                              hipStream_t stream) {
    const float* x = (const float*)d_in[0];   // (256, 131072) fp32
    const float* h = (const float*)d_in[1];   // (1, 16) fp32
    float* y = (float*)d_out;                 // (256, 131072) fp32
    float* g = (float*)d_ws;                  // 33 floats of scratch
    (void)in_sizes; (void)n_in; (void)out_size; (void)ws_size;

    compute_g_kernel<<<1, 64, 0, stream>>>(h, g);
    fir2_kernel<<<PGRID, 256, 0, stream>>>(x, g, h, y);
}

// Round 7
// 269.609 us; speedup vs baseline: 1.1840x; 1.1840x over previous
//
#include <hip/hip_runtime.h>

// Problem: B=256, N=131072, F=16. Two-pass causal FIR with masking.
// For i >= 32, y = 33-tap conv with g = conv([1,h],[1,rev(h)]).
// i in [16,32) explicit; i < 16 zero.
//
// R8 post-mortem: persistent loop serialized on its own nt-stores — the
// per-iteration vmcnt(0) (unroll 1: loads -> wait -> fma -> store) also
// waits the PREVIOUS iteration's HBM store ack (~900cyc). 164us, occ 21%.
// Steady-state FETCH ~ 0: x is fully L3-resident; true floor ~ writes-only.
// R8 -> R9: software-pipelined register double-buffer, named bufs wA/wB
// (static indexing), order: loadB / computeStoreA / loadA' / computeStoreB.
// Compiler emits COUNTED vmcnt -> stores stay in flight, load latency hides
// under 264 cyc of FMA per tile. 4096 WGs x 8 tiles; tile stride 4096 keeps
// blk loop-invariant -> boundary branch hoisted, per-iter addressing = one
// constant pointer add. blk==0 (32 WGs) takes a simple guarded path.

#define NROW 131072
#define NTILES 32768     // 1024 outputs per tile, 128 tiles (columns) per row
#define PGRID 4096       // 8 tiles per WG; stride 4096 tiles = +32 rows, same blk
#define ROWSTEP 32       // PGRID / 128

typedef float f32x4 __attribute__((ext_vector_type(4)));

__global__ void compute_g_kernel(const float* __restrict__ h, float* __restrict__ g) {
    int m = threadIdx.x;
    if (m < 33) {
        float s = 0.f;
#pragma unroll
        for (int a = 0; a <= 16; ++a) {
            int b = m - a;
            if (b >= 0 && b <= 16) {
                float ka = (a == 0) ? 1.f : h[a - 1];
                float kb = (b == 0) ? 1.f : h[16 - b];
                s += ka * kb;
            }
        }
        g[m] = s;
    }
}

#define LOADW(dst, ptr)                                                    \
    do {                                                                   \
        _Pragma("unroll") for (int q = 0; q < 9; ++q) {                    \
            const f32x4 v_ = *(const f32x4*)((ptr) + 4 * q);               \
            (dst)[4 * q + 0] = v_.x; (dst)[4 * q + 1] = v_.y;              \
            (dst)[4 * q + 2] = v_.z; (dst)[4 * q + 3] = v_.w;              \
        }                                                                  \
    } while (0)

__device__ __forceinline__ f32x4 conv4(const float (&w)[36], const float (&gg)[33]) {
    f32x4 o;
#pragma unroll
    for (int c = 0; c < 4; ++c) {
        float s = 0.f;
#pragma unroll
        for (int m = 0; m < 33; ++m) s = fmaf(gg[m], w[c + 32 - m], s);
        o[c] = s;
    }
    return o;
}

__global__ __launch_bounds__(256) void fir2_kernel(const float* __restrict__ x,
                                                   const float* __restrict__ g,
                                                   const float* __restrict__ h,
                                                   float* __restrict__ y) {
    const int t = (int)threadIdx.x;
    const int bid = (int)blockIdx.x;
    const int row0 = bid >> 7;          // starting row; walks row0 + 32j
    const int blk = bid & 127;          // column tile — loop-invariant
    const int p0 = (blk << 10) + 4 * t; // this thread's 4 outputs within row

    // g[0..32]: uniform indices off a uniform pointer -> s_load (SGPRs)
    float gg[33];
#pragma unroll
    for (int m = 0; m < 33; ++m) gg[m] = g[m];

    const size_t STEP = (size_t)ROWSTEP * NROW;     // floats per tile step

    if (blk != 0) {
        // ---- hot path: 8 tiles, reg double-buffer, stores never waited ----
        const float* wp = x + (size_t)row0 * NROW + (p0 - 32);  // p0 >= 1024
        float* sp = y + (size_t)row0 * NROW + p0;

        float wA[36], wB[36];
        LOADW(wA, wp);                                // prologue: tile j=0
#pragma unroll 1
        for (int j = 0; j < 8; j += 2) {
            LOADW(wB, wp + STEP);                     // prefetch tile j+1
            const f32x4 oA = conv4(wA, gg);
            __builtin_nontemporal_store(oA, (f32x4*)sp);
            // prefetch tile j+2 (clamped on last pair: redundant, in-bounds)
            const float* wpn = (j < 6) ? (wp + 2 * STEP) : wp;
            LOADW(wA, wpn);
            const f32x4 oB = conv4(wB, gg);
            __builtin_nontemporal_store(oB, (f32x4*)(sp + STEP));
            wp += 2 * STEP;
            sp += 2 * STEP;
        }
    } else {
        // ---- boundary path: 32 WGs, simple per-tile loop, guarded loads ----
#pragma unroll 1
        for (int j = 0; j < 8; ++j) {
            const int row = row0 + ROWSTEP * j;
            const float* __restrict__ xr = x + (size_t)row * NROW;
            float* __restrict__ yr = y + (size_t)row * NROW;

            float w[36];
#pragma unroll
            for (int q = 0; q < 9; ++q) {
                const int gidx = 4 * t - 32 + 4 * q;
                f32x4 v = (f32x4)(0.f);
                if (gidx >= 0) v = *(const f32x4*)(xr + gidx);
                w[4 * q + 0] = v.x; w[4 * q + 1] = v.y;
                w[4 * q + 2] = v.z; w[4 * q + 3] = v.w;
            }
            f32x4 o = conv4(w, gg);
            __builtin_nontemporal_store(o, (f32x4*)(yr + 4 * t));

            // outputs [0,32): y[i<16]=0; y[16..31] via explicit two-stage
            if (t < 8) {
                f32x4 ofix = (f32x4)(0.f);
                if (t >= 4) {
                    float hh[16];
#pragma unroll
                    for (int jj = 0; jj < 16; ++jj) hh[jj] = h[jj];
                    float vloc[16];
#pragma unroll
                    for (int u = 0; u < 16; ++u) {
                        const int p = 16 + u;
                        float s = xr[p];
#pragma unroll
                        for (int jj = 0; jj < 16; ++jj)
                            s = fmaf(hh[jj], xr[p - 1 - jj], s);
                        vloc[u] = s;
                    }
#pragma unroll
                    for (int p = 16; p < 32; ++p) {
                        float s = vloc[p - 16];
#pragma unroll
                        for (int jj = 0; jj < 16; ++jj)
                            if (jj <= p - 17) s = fmaf(hh[15 - jj], vloc[p - 17 - jj], s);
                        if ((p >> 2) == t) ofix[p & 3] = s;   // static reg index
                    }
                }
                __builtin_nontemporal_store(ofix, (f32x4*)(yr + 4 * t));
            }
        }
    }
}

extern "C" void kernel_launch(void* const* d_in, const int* in_sizes, int n_in,
                              void* d_out, int out_size, void* d_ws, size_t ws_size,
                              hipStream_t stream) {
    const float* x = (const float*)d_in[0];   // (256, 131072) fp32
    const float* h = (const float*)d_in[1];   // (1, 16) fp32
    float* y = (float*)d_out;                 // (256, 131072) fp32
    float* g = (float*)d_ws;                  // 33 floats of scratch
    (void)in_sizes; (void)n_in; (void)out_size; (void)ws_size;

    compute_g_kernel<<<1, 64, 0, stream>>>(h, g);
    fir2_kernel<<<PGRID, 256, 0, stream>>>(x, g, h, y);
}

// Round 8
// 236.359 us; speedup vs baseline: 1.3506x; 1.1407x over previous
//
#include <hip/hip_runtime.h>

// Problem: B=256, N=131072, F=16. Two-pass causal FIR with masking.
// For i >= 32, y = 33-tap conv with g = conv([1,h],[1,rev(h)]).
// i in [16,32) explicit; i < 16 zero.
//
// History: R6 LDS+barrier 82us (occ 41%, conflicts 4.7M, ~18us PADIDX VALU);
// R7 no-LDS one-shot 94us (32768 WGs ~ dispatch wall ~300 WG/us);
// R8/R9 persistent 164/122us (store-ack serialization; VGPR=72 crossed the
// 64-reg occupancy cliff -> waves/SIMD halved).
// R10: wave-autonomous staging. Each wave owns a private 1056-float linear
// LDS region (1024 outputs + 32 halo): staging writes and window reads are
// same-wave ops ordered by compiler lgkmcnt -> NO __syncthreads, no barrier
// convoy. Linear layout: every wave b128 read is contiguous 1KB -> zero
// conflicts, zero pad math. Global loads 1x coalesced; LDS absorbs the 9x
// window amplification at 128B/clk. VGPR ~55 (<64 cliff), LDS 16.9KB,
// 8192 WGs one-shot (100 WG/us, dispatch-safe).

#define NROW 131072
#define TILE 4096        // outputs per WG
#define WTILE 1024       // outputs per wave
#define HALO 32
#define WLDS (WTILE + HALO)   // 1056 floats per wave region

typedef float f32x4 __attribute__((ext_vector_type(4)));

__global__ void compute_g_kernel(const float* __restrict__ h, float* __restrict__ g) {
    int m = threadIdx.x;
    if (m < 33) {
        float s = 0.f;
#pragma unroll
        for (int a = 0; a <= 16; ++a) {
            int b = m - a;
            if (b >= 0 && b <= 16) {
                float ka = (a == 0) ? 1.f : h[a - 1];
                float kb = (b == 0) ? 1.f : h[16 - b];
                s += ka * kb;
            }
        }
        g[m] = s;
    }
}

__device__ __forceinline__ f32x4 conv4(const float (&w)[36], const float (&gg)[33]) {
    f32x4 o;
#pragma unroll
    for (int c = 0; c < 4; ++c) {
        float s = 0.f;
#pragma unroll
        for (int m = 0; m < 33; ++m) s = fmaf(gg[m], w[c + 32 - m], s);
        o[c] = s;
    }
    return o;
}

__global__ __launch_bounds__(256) void fir2_kernel(const float* __restrict__ x,
                                                   const float* __restrict__ g,
                                                   const float* __restrict__ h,
                                                   float* __restrict__ y) {
    __shared__ __align__(16) float lds[4 * WLDS];

    const int bid = blockIdx.x;
    const int row = bid >> 5;           // 32 chunks per row
    const int chunk = bid & 31;
    const int t = (int)threadIdx.x;
    const int wv = t >> 6;              // wave 0..3
    const int l = t & 63;               // lane
    const int i0w = chunk * TILE + wv * WTILE;   // wave's first output
    const float* __restrict__ xr = x + (size_t)row * NROW;
    float* __restrict__ yr = y + (size_t)row * NROW;
    float* const ldsw = lds + wv * WLDS;         // wave-private region

    // g[0..32]: uniform indices off a uniform pointer -> s_load (SGPRs)
    float gg[33];
#pragma unroll
    for (int m = 0; m < 33; ++m) gg[m] = g[m];

    // ---- wave-private stage: x[i0w-32 .. i0w+1024) -> ldsw[0..1056), linear ----
    const int base = i0w - HALO;
    if (chunk == 0 && wv == 0) {        // only wave with gidx < 0
#pragma unroll
        for (int k = 0; k < 4; ++k) {
            const int f = l + 64 * k;
            const int gidx = base + 4 * f;
            f32x4 v = (f32x4)(0.f);
            if (gidx >= 0) v = *(const f32x4*)(xr + gidx);
            *(f32x4*)(ldsw + 4 * f) = v;
        }
    } else {
#pragma unroll
        for (int k = 0; k < 4; ++k) {
            const int f = l + 64 * k;
            f32x4 v = *(const f32x4*)(xr + base + 4 * f);
            *(f32x4*)(ldsw + 4 * f) = v;
        }
    }
    if (l < 8) {                        // halo tail: floats 1024..1055
        const int f = 256 + l;
        f32x4 v = *(const f32x4*)(xr + base + 4 * f);   // gidx = i0w+992+4l >= 0
        *(f32x4*)(ldsw + 4 * f) = v;
    }
    __builtin_amdgcn_wave_barrier();    // compile-time fence: no ds reorder
    // NO __syncthreads(): each wave reads only its own region; lgkmcnt orders.

    // ---- 4 groups; group k: outputs p = i0w + 256k + 4l ----
#pragma unroll 1
    for (int k = 0; k < 4; ++k) {
        const int jb = 256 * k + 4 * l;
        float w[36];
#pragma unroll
        for (int q = 0; q < 9; ++q) {   // contiguous 1KB per wave read inst
            const f32x4 v = *(const f32x4*)(ldsw + jb + 4 * q);
            w[4 * q + 0] = v.x; w[4 * q + 1] = v.y;
            w[4 * q + 2] = v.z; w[4 * q + 3] = v.w;
        }
        const f32x4 o = conv4(w, gg);
        __builtin_nontemporal_store(o, (f32x4*)(yr + i0w + jb));  // contiguous 1KB
    }

    // ---- Cold boundary fixup: outputs [0,32), chunk 0, lanes 0..7 (wave 0) ----
    if (chunk == 0 && t < 8) {          // ldsw == lds here; x[i] = ldsw[i+32]
        f32x4 ofix = (f32x4)(0.f);
        if (t >= 4) {
            float hh[16];
#pragma unroll
            for (int j = 0; j < 16; ++j) hh[j] = h[j];   // uniform -> s_load
            // v[16+u] = x[16+u] + sum_j h[j] x[15+u-j]
            float vloc[16];
#pragma unroll
            for (int u = 0; u < 16; ++u) {
                const int p = 16 + u;
                float s = ldsw[p + 32];
#pragma unroll
                for (int j = 0; j < 16; ++j)
                    s = fmaf(hh[j], ldsw[p + 31 - j], s);
                vloc[u] = s;
            }
            // y[p] = v[p] + sum_{j<=p-17} h[15-j] v[p-1-j]; static indexing
#pragma unroll
            for (int p = 16; p < 32; ++p) {
                float s = vloc[p - 16];
#pragma unroll
                for (int j = 0; j < 16; ++j)
                    if (j <= p - 17) s = fmaf(hh[15 - j], vloc[p - 17 - j], s);
                if ((p >> 2) == t) ofix[p & 3] = s;      // static reg index
            }
        }
        __builtin_nontemporal_store(ofix, (f32x4*)(yr + 4 * t));  // overwrite
    }
}

extern "C" void kernel_launch(void* const* d_in, const int* in_sizes, int n_in,
                              void* d_out, int out_size, void* d_ws, size_t ws_size,
                              hipStream_t stream) {
    const float* x = (const float*)d_in[0];   // (256, 131072) fp32
    const float* h = (const float*)d_in[1];   // (1, 16) fp32
    float* y = (float*)d_out;                 // (256, 131072) fp32
    float* g = (float*)d_ws;                  // 33 floats of scratch
    (void)in_sizes; (void)n_in; (void)out_size; (void)ws_size;

    compute_g_kernel<<<1, 64, 0, stream>>>(h, g);
    fir2_kernel<<<8192, 256, 0, stream>>>(x, g, h, y);
}